// Round 1
// baseline (125.383 us; speedup 1.0000x reference)
//
#include <hip/hip_runtime.h>
#include <hip/hip_bf16.h>

#define LEVEL 256
#define BLOCKS 8
// B=16, H=W=1024, bm=bn=128, tv = 16384/256*10 = 640

// ---------------------------------------------------------------------------
// Kernel 1: per-image-block histogram -> clip -> cdf -> map table
// grid = 16*8*8 = 1024 blocks, 256 threads each.
// maps layout in ws: float maps[B=16][8][8][256]
// ---------------------------------------------------------------------------
__global__ __launch_bounds__(256) void clahe_hist_kernel(const float* __restrict__ img,
                                                         float* __restrict__ maps) {
    __shared__ int   hist[256];
    __shared__ float red[256];
    __shared__ float scan[256];
    __shared__ float s_me;

    const int t   = threadIdx.x;
    const int bid = blockIdx.x;            // 0..1023
    const int b   = bid >> 6;              // image
    const int blk = bid & 63;
    const int br  = blk >> 3;
    const int bc  = blk & 7;

    hist[t] = 0;
    __syncthreads();

    // 128x128 block = 4096 float4 loads, 16 per thread, coalesced
    const size_t base = (size_t)b * 1048576 + (size_t)(br * 128) * 1024 + (size_t)(bc * 128);
    const float* p = img + base;
    for (int it = 0; it < 16; ++it) {
        int idx = it * 256 + t;            // 0..4095
        int y   = idx >> 5;                // 0..127
        int x   = (idx & 31) * 4;          // 0..124
        float4 v = *(const float4*)(p + (size_t)y * 1024 + x);
        atomicAdd(&hist[(int)v.x], 1);
        atomicAdd(&hist[(int)v.y], 1);
        atomicAdd(&hist[(int)v.z], 1);
        atomicAdd(&hist[(int)v.w], 1);
    }
    __syncthreads();

    // clip: tv = 640, redistribute excess uniformly (all integer-exact in fp32)
    const float tv = 640.0f;
    float h = (float)hist[t];
    float extra = fmaxf(h - tv, 0.0f);
    red[t] = extra;
    __syncthreads();
    for (int off = 128; off > 0; off >>= 1) {
        if (t < off) red[t] += red[t + off];
        __syncthreads();
    }
    if (t == 0) s_me = red[0] * (1.0f / 256.0f);   // exact: /2^8
    __syncthreads();
    const float me = s_me;
    float clip = floorf(((h >= tv) ? tv : h) + me);

    // inclusive scan over 256 bins (integer-valued -> exact any order)
    scan[t] = clip;
    __syncthreads();
    for (int off = 1; off < 256; off <<= 1) {
        float add = (t >= off) ? scan[t - off] : 0.0f;
        __syncthreads();
        scan[t] += add;
        __syncthreads();
    }
    float cdf = scan[t] * (255.0f / 16384.0f);     // exact scale: 255/2^14
    int m = ((int)floorf(cdf)) & 255;
    maps[(size_t)bid * 256 + t] = (float)m;
}

// ---------------------------------------------------------------------------
// Kernel 2: per-pixel bilinear blend of 4 neighboring block maps.
// 64x64 pixel tile per workgroup (r,c constant within a 64-aligned tile since
// interpolation boundaries are at i = 64 + 128*m). 4 maps staged in LDS.
// grid = (16, 16, 16) = (W/64, H/64, B), 256 threads.
// ---------------------------------------------------------------------------
__global__ __launch_bounds__(256) void clahe_map_kernel(const float* __restrict__ img,
                                                        const float* __restrict__ maps,
                                                        float* __restrict__ out) {
#pragma clang fp contract(off)
    __shared__ float m_lu[256], m_lb[256], m_ru[256], m_rb[256];

    const int t  = threadIdx.x;
    const int b  = blockIdx.z;
    const int i0 = blockIdx.y * 64;
    const int j0 = blockIdx.x * 64;

    // r = trunc((i-64)/128) toward zero, constant over the tile
    const int r  = (i0 >= 64) ? ((i0 - 64) >> 7) : 0;
    const int c  = (j0 >= 64) ? ((j0 - 64) >> 7) : 0;
    const int rp = min(r + 1, BLOCKS - 1);
    const int cp = min(c + 1, BLOCKS - 1);
    const bool rEdge = (r >= BLOCKS - 1);
    const bool cEdge = (c >= BLOCKS - 1);

    const float* mb = maps + (size_t)b * 64 * 256;
    m_lu[t] = mb[(r  * 8 + c ) * 256 + t];
    m_lb[t] = mb[(rp * 8 + c ) * 256 + t];
    m_ru[t] = mb[(r  * 8 + cp) * 256 + t];
    m_rb[t] = mb[(rp * 8 + cp) * 256 + t];
    __syncthreads();

    const size_t ibase = (size_t)b * 1048576;
    const int row_in = t >> 4;          // 0..15
    const int col4   = (t & 15) * 4;    // 0..60

    for (int it = 0; it < 4; ++it) {
        const int i = i0 + it * 16 + row_in;
        const int j = j0 + col4;
        const float4 px = *(const float4*)(img + ibase + (size_t)i * 1024 + j);

        float x1 = rEdge ? 0.0f : ((float)i - (float)(r * 128 + 64)) * 0.0078125f;

        float vals[4] = {px.x, px.y, px.z, px.w};
        float4 o4;
        float* ov = (float*)&o4;
        for (int k = 0; k < 4; ++k) {
            const int jj = j + k;
            float y1 = cEdge ? 0.0f : ((float)jj - (float)(c * 128 + 64)) * 0.0078125f;
            const int vv = (int)vals[k];
            const float lu = m_lu[vv];
            const float lb = m_lb[vv];
            const float ru = m_ru[vv];
            const float rb = m_rb[vv];
            // exact expression order of the reference; no FMA contraction
            float o = (1.0f - y1) * ((1.0f - x1) * lu + x1 * lb)
                    + y1 * ((1.0f - x1) * ru + x1 * rb);
            // trunc toward zero then floor-mod 256 (two's-complement & 255)
            ov[k] = (float)(((int)o) & 255);
        }
        *(float4*)(out + ibase + (size_t)i * 1024 + j) = o4;
    }
}

extern "C" void kernel_launch(void* const* d_in, const int* in_sizes, int n_in,
                              void* d_out, int out_size, void* d_ws, size_t ws_size,
                              hipStream_t stream) {
    const float* img = (const float*)d_in[0];
    float* out = (float*)d_out;
    float* maps = (float*)d_ws;   // 16*64*256 floats = 1 MB

    clahe_hist_kernel<<<dim3(1024), dim3(256), 0, stream>>>(img, maps);
    clahe_map_kernel<<<dim3(16, 16, 16), dim3(256), 0, stream>>>(img, maps, out);
}

// Round 2
// 124.011 us; speedup vs baseline: 1.0111x; 1.0111x over previous
//
#include <hip/hip_runtime.h>
#include <hip/hip_bf16.h>

#define LEVEL 256
#define BLOCKS 8
// B=16, H=W=1024, bm=bn=128, tv = 16384/256*10 = 640

// ---------------------------------------------------------------------------
// Kernel 1: per-image-block histogram -> clip -> cdf -> map table.
// Optionally also stages the pixel values as uint8 into ws so kernel 2 reads
// 16 MB instead of 64 MB.
// grid = 16*8*8 = 1024 blocks, 256 threads each.
// maps layout in ws: float maps[B=16][8][8][256]
// ---------------------------------------------------------------------------
__global__ __launch_bounds__(256) void clahe_hist_kernel(const float* __restrict__ img,
                                                         float* __restrict__ maps,
                                                         unsigned char* __restrict__ u8img) {
    __shared__ int   hist[256];
    __shared__ float red[256];
    __shared__ float scan[256];
    __shared__ float s_me;

    const int t   = threadIdx.x;
    const int bid = blockIdx.x;            // 0..1023
    const int b   = bid >> 6;              // image
    const int blk = bid & 63;
    const int br  = blk >> 3;
    const int bc  = blk & 7;

    hist[t] = 0;
    __syncthreads();

    // 128x128 block = 4096 float4 loads, 16 per thread, coalesced
    const size_t base = (size_t)b * 1048576 + (size_t)(br * 128) * 1024 + (size_t)(bc * 128);
    const float* p = img + base;
    unsigned char* q8 = u8img ? (u8img + base) : nullptr;
    for (int it = 0; it < 16; ++it) {
        int idx = it * 256 + t;            // 0..4095
        int y   = idx >> 5;                // 0..127
        int x   = (idx & 31) * 4;          // 0..124
        float4 v = *(const float4*)(p + (size_t)y * 1024 + x);
        int va = (int)v.x, vb = (int)v.y, vc = (int)v.z, vd = (int)v.w;
        atomicAdd(&hist[va], 1);
        atomicAdd(&hist[vb], 1);
        atomicAdd(&hist[vc], 1);
        atomicAdd(&hist[vd], 1);
        if (q8) {
            uchar4 pk;
            pk.x = (unsigned char)va; pk.y = (unsigned char)vb;
            pk.z = (unsigned char)vc; pk.w = (unsigned char)vd;
            *(uchar4*)(q8 + (size_t)y * 1024 + x) = pk;
        }
    }
    __syncthreads();

    // clip: tv = 640, redistribute excess uniformly (all integer-exact in fp32)
    const float tv = 640.0f;
    float h = (float)hist[t];
    float extra = fmaxf(h - tv, 0.0f);
    red[t] = extra;
    __syncthreads();
    for (int off = 128; off > 0; off >>= 1) {
        if (t < off) red[t] += red[t + off];
        __syncthreads();
    }
    if (t == 0) s_me = red[0] * (1.0f / 256.0f);   // exact: /2^8
    __syncthreads();
    const float me = s_me;
    float clip = floorf(((h >= tv) ? tv : h) + me);

    // inclusive scan over 256 bins (integer-valued -> exact any order)
    scan[t] = clip;
    __syncthreads();
    for (int off = 1; off < 256; off <<= 1) {
        float add = (t >= off) ? scan[t - off] : 0.0f;
        __syncthreads();
        scan[t] += add;
        __syncthreads();
    }
    float cdf = scan[t] * (255.0f / 16384.0f);     // exact scale: 255/2^14
    int m = ((int)floorf(cdf)) & 255;
    maps[(size_t)bid * 256 + t] = (float)m;
}

// ---------------------------------------------------------------------------
// Kernel 2: per-pixel bilinear blend of 4 neighboring block maps.
// 64x64 pixel tile per workgroup (r,c constant within a 64-aligned tile since
// interpolation boundaries sit at i = 64 + 128*m). The 4 maps are interleaved
// into one float4[256] LDS table -> single ds_read_b128 per pixel.
// grid = (16, 16, 16) = (W/64, H/64, B), 256 threads.
// U8 variant reads the staged uint8 image (16 MB) instead of floats (64 MB).
// ---------------------------------------------------------------------------
template <bool U8>
__global__ __launch_bounds__(256) void clahe_map_kernel(const float* __restrict__ imgf,
                                                        const unsigned char* __restrict__ img8,
                                                        const float* __restrict__ maps,
                                                        float* __restrict__ out) {
#pragma clang fp contract(off)
    __shared__ float4 m4[256];   // {lu, lb, ru, rb} per bin

    const int t  = threadIdx.x;
    const int b  = blockIdx.z;
    const int i0 = blockIdx.y * 64;
    const int j0 = blockIdx.x * 64;

    // r = trunc((i-64)/128) toward zero, constant over the tile
    const int r  = (i0 >= 64) ? ((i0 - 64) >> 7) : 0;
    const int c  = (j0 >= 64) ? ((j0 - 64) >> 7) : 0;
    const int rp = min(r + 1, BLOCKS - 1);
    const int cp = min(c + 1, BLOCKS - 1);
    const bool rEdge = (r >= BLOCKS - 1);
    const bool cEdge = (c >= BLOCKS - 1);

    const float* mb = maps + (size_t)b * 64 * 256;
    {
        float lu = mb[(r  * 8 + c ) * 256 + t];
        float lb = mb[(rp * 8 + c ) * 256 + t];
        float ru = mb[(r  * 8 + cp) * 256 + t];
        float rb = mb[(rp * 8 + cp) * 256 + t];
        m4[t] = make_float4(lu, lb, ru, rb);
    }
    __syncthreads();

    const size_t ibase = (size_t)b * 1048576;
    const int row_in = t >> 4;          // 0..15
    const int col4   = (t & 15) * 4;    // 0..60

    for (int it = 0; it < 4; ++it) {
        const int i = i0 + it * 16 + row_in;
        const int j = j0 + col4;

        int vv[4];
        if (U8) {
            uchar4 px = *(const uchar4*)(img8 + ibase + (size_t)i * 1024 + j);
            vv[0] = px.x; vv[1] = px.y; vv[2] = px.z; vv[3] = px.w;
        } else {
            float4 px = *(const float4*)(imgf + ibase + (size_t)i * 1024 + j);
            vv[0] = (int)px.x; vv[1] = (int)px.y; vv[2] = (int)px.z; vv[3] = (int)px.w;
        }

        const float x1  = rEdge ? 0.0f : ((float)i - (float)(r * 128 + 64)) * 0.0078125f;
        const float x0  = 1.0f - x1;

        float4 o4;
        float* ov = (float*)&o4;
        for (int k = 0; k < 4; ++k) {
            const int jj = j + k;
            const float y1 = cEdge ? 0.0f : ((float)jj - (float)(c * 128 + 64)) * 0.0078125f;
            const float4 q = m4[vv[k]];
            // exact expression order of the reference; no FMA contraction
            float o = (1.0f - y1) * (x0 * q.x + x1 * q.y)
                    + y1 * (x0 * q.z + x1 * q.w);
            // trunc toward zero then floor-mod 256 (two's-complement & 255)
            ov[k] = (float)(((int)o) & 255);
        }
        *(float4*)(out + ibase + (size_t)i * 1024 + j) = o4;
    }
}

extern "C" void kernel_launch(void* const* d_in, const int* in_sizes, int n_in,
                              void* d_out, int out_size, void* d_ws, size_t ws_size,
                              hipStream_t stream) {
    const float* img = (const float*)d_in[0];
    float* out = (float*)d_out;
    float* maps = (float*)d_ws;                       // 1 MB: 16*64*256 floats

    const size_t maps_bytes = (size_t)1024 * 256 * sizeof(float);
    const size_t u8_bytes   = (size_t)16 * 1024 * 1024;
    const bool use_u8 = ws_size >= maps_bytes + u8_bytes;
    unsigned char* u8img = use_u8 ? ((unsigned char*)d_ws + maps_bytes) : nullptr;

    clahe_hist_kernel<<<dim3(1024), dim3(256), 0, stream>>>(img, maps, u8img);
    if (use_u8) {
        clahe_map_kernel<true><<<dim3(16, 16, 16), dim3(256), 0, stream>>>(
            nullptr, u8img, maps, out);
    } else {
        clahe_map_kernel<false><<<dim3(16, 16, 16), dim3(256), 0, stream>>>(
            img, nullptr, maps, out);
    }
}